// Round 12
// baseline (256.779 us; speedup 1.0000x reference)
//
#include <hip/hip_runtime.h>
#include <hip/hip_bf16.h>

#define BB 32
#define NN 128
#define SD 128
#define ED 32
#define ID 256
#define BN (BB*NN)   // 4096
#define NI 4         // i-blocks per k2 workgroup

// Bprep tile index bases
#define WM2B 288
#define WU1B 352
#define WU2B 480

typedef __attribute__((ext_vector_type(8))) short sh8;
typedef __attribute__((ext_vector_type(4))) float f32x4;

__device__ __forceinline__ float ftanh(float x) {
    float e2 = __expf(2.0f * x);
    return 1.0f - 2.0f * __builtin_amdgcn_rcpf(e2 + 1.0f);
}

__device__ __forceinline__ ushort f2bf(float f) {
    unsigned u = __float_as_uint(f);
    return (ushort)((u + 0x7FFF + ((u >> 16) & 1)) >> 16);
}

// build a bf16 A-frag (rows 0..3 real, 4..15 zero) from f32 LDS rows
__device__ __forceinline__ sh8 afragT(const float* base, int stride, int kt, int lane) {
    sh8 v = (sh8){0, 0, 0, 0, 0, 0, 0, 0};
    if ((lane & 15) < 4) {
        const float* p = base + (lane & 15) * stride + kt * 32 + (lane >> 4) * 8;
        f32x4 a0 = *(const f32x4*)p;
        f32x4 a1 = *(const f32x4*)(p + 4);
        v[0] = (short)f2bf(a0[0]); v[1] = (short)f2bf(a0[1]);
        v[2] = (short)f2bf(a0[2]); v[3] = (short)f2bf(a0[3]);
        v[4] = (short)f2bf(a1[0]); v[5] = (short)f2bf(a1[1]);
        v[6] = (short)f2bf(a1[2]); v[7] = (short)f2bf(a1[3]);
    }
    return v;
}

// ---------------------------------------------------------------------------
// k_prep: frag-ordered bf16 B-tiles (layout identical to R11).
// grid 544, block 64
// ---------------------------------------------------------------------------
__global__ void k_prep(const float* __restrict__ Wg1, const float* __restrict__ Wm1,
                       const float* __restrict__ Wm2, const float* __restrict__ Wu1,
                       const float* __restrict__ Wu2, ushort* __restrict__ Bprep) {
    const int tt = blockIdx.x;
    const int l = threadIdx.x;
    const float* W;
    int rowbase, nt, stride;
    if (tt < 256) {
        const int tgt = tt >> 6;
        const int kt = (tt >> 4) & 3;
        nt = tt & 15;
        W = (tgt >= 2) ? Wm1 : Wg1;
        rowbase = (tgt & 1) * 128 + kt * 32;
        stride = ID;
    } else if (tt < WM2B) {
        const int wt = tt - 256;
        W = (wt >> 4) ? Wm1 : Wg1;
        rowbase = 2 * SD;
        nt = wt & 15;
        stride = ID;
    } else if (tt < WU1B) {
        const int wt = tt - WM2B;
        W = Wm2; rowbase = (wt >> 3) * 32; nt = wt & 7; stride = SD;
    } else if (tt < WU2B) {
        const int wt = tt - WU1B;
        W = Wu1; rowbase = (wt >> 4) * 32; nt = wt & 15; stride = ID;
    } else {
        const int wt = tt - WU2B;
        W = Wu2; rowbase = (wt >> 3) * 32; nt = wt & 7; stride = SD;
    }
    const int colw = nt * 16 + (l & 15);
    const int kb = rowbase + (l >> 4) * 8;
    sh8 v;
    #pragma unroll
    for (int e = 0; e < 8; ++e)
        v[e] = (short)f2bf(W[(size_t)(kb + e) * stride + colw]);
    *(sh8*)&Bprep[(size_t)tt * 512 + l * 8] = v;
}

// ---------------------------------------------------------------------------
// K1 (MFMA): one 16-row stripe x one target per block (grid.y = tgt).
// grid (BN/16, 4), block 256
// ---------------------------------------------------------------------------
__global__ __launch_bounds__(256) void k1_mfma(
        const float* __restrict__ h,
        const float* __restrict__ bg1, const float* __restrict__ bm1,
        const ushort* __restrict__ Bprep,
        float* __restrict__ Hgi, float* __restrict__ Hgjt,
        float* __restrict__ Hmi, float* __restrict__ Hmjt) {
    const int blk = blockIdx.x;
    const int tgt = blockIdx.y;
    const int t = threadIdx.x;
    const int w = t >> 6;
    const int lane = t & 63;
    const int col = lane & 15;
    const int grp = lane >> 4;
    __shared__ __align__(16) ushort Alds[4 * 512];

    {   // stage h rows -> bf16 frag order
        const int c = t;
        const int kt = c >> 6, l = c & 63;
        const int row = l & 15;
        const int kb = kt * 32 + (l >> 4) * 8;
        const float* p = h + (size_t)(blk * 16 + row) * SD + kb;
        f32x4 a0 = *(const f32x4*)p;
        f32x4 a1 = *(const f32x4*)(p + 4);
        sh8 v;
        v[0] = (short)f2bf(a0[0]); v[1] = (short)f2bf(a0[1]);
        v[2] = (short)f2bf(a0[2]); v[3] = (short)f2bf(a0[3]);
        v[4] = (short)f2bf(a1[0]); v[5] = (short)f2bf(a1[1]);
        v[6] = (short)f2bf(a1[2]); v[7] = (short)f2bf(a1[3]);
        *(sh8*)&Alds[c * 8] = v;
    }
    __syncthreads();

    const int kcol = w * 64 + col;
    sh8 Af[4];
    #pragma unroll
    for (int kt = 0; kt < 4; ++kt)
        Af[kt] = *(const sh8*)&Alds[kt * 512 + lane * 8];

    f32x4 acc[4];
    #pragma unroll
    for (int n = 0; n < 4; ++n) acc[n] = (f32x4){0.f, 0.f, 0.f, 0.f};
    #pragma unroll
    for (int kt = 0; kt < 4; ++kt)
        #pragma unroll
        for (int n = 0; n < 4; ++n) {
            sh8 Bf = *(const sh8*)&Bprep[
                (size_t)(tgt * 64 + kt * 16 + w * 4 + n) * 512 + lane * 8];
            acc[n] = __builtin_amdgcn_mfma_f32_16x16x32_bf16(
                Af[kt], Bf, acc[n], 0, 0, 0);
        }
    if (tgt & 1) {
        float* out = (tgt == 1) ? Hgjt : Hmjt;
        #pragma unroll
        for (int n = 0; n < 4; ++n)
            *(f32x4*)&out[((size_t)blk * ID + kcol + n * 16) * 16 + grp * 4] = acc[n];
    } else {
        const float* bias = (tgt == 0) ? bg1 : bm1;
        float* out = (tgt == 0) ? Hgi : Hmi;
        #pragma unroll
        for (int n = 0; n < 4; ++n) {
            const float bv = bias[kcol + n * 16];
            #pragma unroll
            for (int r = 0; r < 4; ++r)
                out[(size_t)(blk * 16 + grp * 4 + r) * ID + kcol + n * 16] =
                    acc[n][r] + bv;
        }
    }
}

// ---------------------------------------------------------------------------
// K2 fused, j-halved: per half {stage 16KB E, gate, sigmoid, msg}. LDS ~18.6KB
// -> 8 blocks/CU. Tail (agg/FC1/FC2 MFMA + LN) unchanged from R11.
// grid BN/NI, block 256
// ---------------------------------------------------------------------------
__global__ __launch_bounds__(256, 8) void k2_fused(
        const float* __restrict__ ef, const float* __restrict__ em,
        const ushort* __restrict__ Bprep,
        const float* __restrict__ Hgi, const float* __restrict__ Hmi,
        const float* __restrict__ Hgjt, const float* __restrict__ Hmjt,
        const float* __restrict__ Wg2, const float* __restrict__ bg2,
        const float* __restrict__ h,
        const float* __restrict__ Wu1, const float* __restrict__ bu1,
        const float* __restrict__ bu2, const float* __restrict__ bm2,
        const float* __restrict__ lnw, const float* __restrict__ lnb,
        float* __restrict__ out) {
    const int bi0 = blockIdx.x * NI;
    const int b = bi0 >> 7;
    const int t = threadIdx.x;
    const int w = t >> 6;
    const int lane = t & 63;
    const int col = lane & 15;
    const int grp = lane >> 4;

    __shared__ __align__(16) ushort Elds[NI * 4 * 512];   // 16 KB
    __shared__ float glds[NI][NN];                        // 2 KB
    __shared__ float gsumL[NI], degL[NI];

    {
        float* gl = &glds[0][0];
        gl[t] = 0.f;
        gl[t + 256] = 0.f;
    }

    const int kcol = w * 64 + col;
    const float* HgjL = Hgjt + (size_t)b * 8 * ID * 16 + (size_t)kcol * 16 + grp * 4;
    const float* HmjL = Hmjt + (size_t)b * 8 * ID * 16 + (size_t)kcol * 16 + grp * 4;
    const float bg2v = bg2[0];

    float ts[NI][4];
    #pragma unroll
    for (int i = 0; i < NI; ++i)
        #pragma unroll
        for (int n = 0; n < 4; ++n) ts[i][n] = 0.f;
    float gs_run = 0.f, dv_run = 0.f;

    for (int half = 0; half < 2; ++half) {
        __syncthreads();   // protect Elds from previous half's msg readers
        // ---- stage E for this half (frag-ordered, conflict-free)
        #pragma unroll
        for (int i = 0; i < NI; ++i) {
            const float* efb = ef + (size_t)(bi0 + i) * NN * ED;
            const int c = t;                               // chunk 0..255
            const int j = (half * 4 + (c >> 6)) * 16 + (c & 15);
            const int kb = ((c >> 4) & 3) * 8;
            const float* p = efb + j * ED + kb;
            f32x4 a0 = *(const f32x4*)p;
            f32x4 a1 = *(const f32x4*)(p + 4);
            sh8 v;
            v[0] = (short)f2bf(a0[0]); v[1] = (short)f2bf(a0[1]);
            v[2] = (short)f2bf(a0[2]); v[3] = (short)f2bf(a0[3]);
            v[4] = (short)f2bf(a1[0]); v[5] = (short)f2bf(a1[1]);
            v[6] = (short)f2bf(a1[2]); v[7] = (short)f2bf(a1[3]);
            *(sh8*)&Elds[i * 2048 + c * 8] = v;
        }
        __syncthreads();

        // ================= gate pass (4 s-tiles of this half)
        {
            sh8 Bg[4];
            float hgiR[NI][4], wg2R[4];
            #pragma unroll
            for (int n = 0; n < 4; ++n) {
                Bg[n] = *(const sh8*)&Bprep[(size_t)(256 + w * 4 + n) * 512 + lane * 8];
                wg2R[n] = Wg2[kcol + n * 16];
            }
            #pragma unroll
            for (int i = 0; i < NI; ++i)
                #pragma unroll
                for (int n = 0; n < 4; ++n)
                    hgiR[i][n] = Hgi[(size_t)(bi0 + i) * ID + kcol + n * 16];
            const float* Hbase = HgjL + (size_t)(half * 4) * (ID * 16);
            f32x4 Cg[4], Cn[4];
            #pragma unroll
            for (int n = 0; n < 4; ++n) Cg[n] = *(const f32x4*)(Hbase + n * 256);
            for (int st = 0; st < 4; ++st) {
                if (st < 3) {
                    const float* ps = Hbase + (size_t)(st + 1) * (ID * 16);
                    #pragma unroll
                    for (int n = 0; n < 4; ++n) Cn[n] = *(const f32x4*)(ps + n * 256);
                }
                #pragma unroll
                for (int i = 0; i < NI; ++i) {
                    sh8 Af = *(const sh8*)&Elds[i * 2048 + st * 512 + lane * 8];
                    f32x4 acc[4];
                    #pragma unroll
                    for (int n = 0; n < 4; ++n)
                        acc[n] = __builtin_amdgcn_mfma_f32_16x16x32_bf16(
                            Af, Bg[n], Cg[n], 0, 0, 0);
                    float p[4] = {0.f, 0.f, 0.f, 0.f};
                    #pragma unroll
                    for (int n = 0; n < 4; ++n)
                        #pragma unroll
                        for (int r = 0; r < 4; ++r)
                            p[r] = fmaf(ftanh(acc[n][r] + hgiR[i][n]), wg2R[n], p[r]);
                    #pragma unroll
                    for (int m = 1; m < 16; m <<= 1)
                        #pragma unroll
                        for (int r = 0; r < 4; ++r) p[r] += __shfl_xor(p[r], m, 64);
                    if (col == 0) {
                        #pragma unroll
                        for (int r = 0; r < 4; ++r)
                            atomicAdd(&glds[i][(half * 4 + st) * 16 + grp * 4 + r],
                                      p[r]);
                    }
                }
                #pragma unroll
                for (int n = 0; n < 4; ++n) Cg[n] = Cn[n];
            }
        }
        __syncthreads();

        // ---- sigmoid + mask for this half's j (wave w -> i=w)
        {
            const int j = half * 64 + lane;
            const float pre = glds[w][j] + bg2v;
            const float m = em[(size_t)(bi0 + w) * NN + j];
            const float g = m * __builtin_amdgcn_rcpf(1.0f + __expf(-pre));
            glds[w][j] = g;
            gs_run += g;
            dv_run += m;
        }
        __syncthreads();

        // ================= msg pass (4 s-tiles of this half)
        {
            sh8 Bm[4];
            float hmiR[NI][4];
            #pragma unroll
            for (int n = 0; n < 4; ++n)
                Bm[n] = *(const sh8*)&Bprep[(size_t)(272 + w * 4 + n) * 512 + lane * 8];
            #pragma unroll
            for (int i = 0; i < NI; ++i)
                #pragma unroll
                for (int n = 0; n < 4; ++n)
                    hmiR[i][n] = Hmi[(size_t)(bi0 + i) * ID + kcol + n * 16];
            const float* Hbase = HmjL + (size_t)(half * 4) * (ID * 16);
            f32x4 Cm[4], Cn[4];
            #pragma unroll
            for (int n = 0; n < 4; ++n) Cm[n] = *(const f32x4*)(Hbase + n * 256);
            for (int st = 0; st < 4; ++st) {
                if (st < 3) {
                    const float* ps = Hbase + (size_t)(st + 1) * (ID * 16);
                    #pragma unroll
                    for (int n = 0; n < 4; ++n) Cn[n] = *(const f32x4*)(ps + n * 256);
                }
                #pragma unroll
                for (int i = 0; i < NI; ++i) {
                    sh8 Af = *(const sh8*)&Elds[i * 2048 + st * 512 + lane * 8];
                    f32x4 acc[4];
                    #pragma unroll
                    for (int n = 0; n < 4; ++n)
                        acc[n] = __builtin_amdgcn_mfma_f32_16x16x32_bf16(
                            Af, Bm[n], Cm[n], 0, 0, 0);
                    f32x4 gr = *(const f32x4*)&glds[i][(half * 4 + st) * 16 + grp * 4];
                    #pragma unroll
                    for (int n = 0; n < 4; ++n)
                        #pragma unroll
                        for (int r = 0; r < 4; ++r)
                            ts[i][n] = fmaf(gr[r], ftanh(acc[n][r] + hmiR[i][n]),
                                            ts[i][n]);
                }
                #pragma unroll
                for (int n = 0; n < 4; ++n) Cm[n] = Cn[n];
            }
        }
    }

    // ---- final gsum/deg reduce (wave w owns i=w)
    #pragma unroll
    for (int mm = 1; mm < 64; mm <<= 1) {
        gs_run += __shfl_xor(gs_run, mm, 64);
        dv_run += __shfl_xor(dv_run, mm, 64);
    }
    if (lane == 0) { gsumL[w] = gs_run; degL[w] = dv_run; }

    // ---- ts k-reduce
    #pragma unroll
    for (int i = 0; i < NI; ++i)
        #pragma unroll
        for (int n = 0; n < 4; ++n) {
            ts[i][n] += __shfl_xor(ts[i][n], 16, 64);
            ts[i][n] += __shfl_xor(ts[i][n], 32, 64);
        }

    // ================= MFMA tail (reuse Elds as f32 scratch)
    __syncthreads();                      // Elds reads done; gsumL/degL visible
    float* scratch = (float*)Elds;
    float* Tl  = scratch;                 // [4][256]
    float* up  = scratch + 1024;          // [4][260]
    float* uu  = scratch + 2064;          // [4][256]
    float* xsb = scratch + 3088;          // [4][128]
    if (lane < 16) {
        #pragma unroll
        for (int i = 0; i < NI; ++i)
            #pragma unroll
            for (int n = 0; n < 4; ++n)
                Tl[i * 256 + w * 64 + n * 16 + lane] = ts[i][n];
    }
    #pragma unroll
    for (int it = 0; it < 2; ++it) {
        const int idx = it * 256 + t;
        const int i = idx >> 7, c = idx & 127;
        up[i * 260 + c] = h[(size_t)(bi0 + i) * SD + c];
    }
    if (t < NI) up[t * 260 + 256] = degL[t] * (1.0f / 127.0f);
    __syncthreads();

    {   // agg: up[i][128+d] = (T@Wm2 + g*bm2)/max(g,1); wave w -> nt {2w,2w+1}
        f32x4 acc[2];
        acc[0] = (f32x4){0.f, 0.f, 0.f, 0.f};
        acc[1] = (f32x4){0.f, 0.f, 0.f, 0.f};
        #pragma unroll
        for (int kt = 0; kt < 8; ++kt) {
            sh8 Af = afragT(Tl, 256, kt, lane);
            #pragma unroll
            for (int n2 = 0; n2 < 2; ++n2) {
                sh8 Bf = *(const sh8*)&Bprep[
                    (size_t)(WM2B + kt * 8 + w * 2 + n2) * 512 + lane * 8];
                acc[n2] = __builtin_amdgcn_mfma_f32_16x16x32_bf16(Af, Bf, acc[n2], 0, 0, 0);
            }
        }
        if (grp == 0) {
            #pragma unroll
            for (int n2 = 0; n2 < 2; ++n2) {
                const int d = (w * 2 + n2) * 16 + lane;
                const float bmv = bm2[d];
                #pragma unroll
                for (int r = 0; r < 4; ++r) {
                    const float g = gsumL[r];
                    up[r * 260 + SD + d] = fmaf(g, bmv, acc[n2][r]) *
                                           __builtin_amdgcn_rcpf(fmaxf(g, 1.0f));
                }
            }
        }
    }
    __syncthreads();

    {   // FC1: uu = tanh(up@Wu1 + bu1 + deg-row); wave w -> nt {4w..4w+3}
        f32x4 acc[4];
        #pragma unroll
        for (int n2 = 0; n2 < 4; ++n2) acc[n2] = (f32x4){0.f, 0.f, 0.f, 0.f};
        #pragma unroll
        for (int kt = 0; kt < 8; ++kt) {
            sh8 Af = afragT(up, 260, kt, lane);
            #pragma unroll
            for (int n2 = 0; n2 < 4; ++n2) {
                sh8 Bf = *(const sh8*)&Bprep[
                    (size_t)(WU1B + kt * 16 + w * 4 + n2) * 512 + lane * 8];
                acc[n2] = __builtin_amdgcn_mfma_f32_16x16x32_bf16(Af, Bf, acc[n2], 0, 0, 0);
            }
        }
        if (grp == 0) {
            #pragma unroll
            for (int n2 = 0; n2 < 4; ++n2) {
                const int kc = (w * 4 + n2) * 16 + lane;
                const float wdeg = Wu1[(size_t)(2 * SD) * ID + kc];
                const float bb = bu1[kc];
                #pragma unroll
                for (int r = 0; r < 4; ++r)
                    uu[r * 256 + kc] =
                        ftanh(acc[n2][r] + bb + up[r * 260 + 256] * wdeg);
            }
        }
    }
    __syncthreads();

    {   // FC2 + residual: xs = h + tanh(uu@Wu2 + bu2); wave w -> nt {2w,2w+1}
        f32x4 acc[2];
        acc[0] = (f32x4){0.f, 0.f, 0.f, 0.f};
        acc[1] = (f32x4){0.f, 0.f, 0.f, 0.f};
        #pragma unroll
        for (int kt = 0; kt < 8; ++kt) {
            sh8 Af = afragT(uu, 256, kt, lane);
            #pragma unroll
            for (int n2 = 0; n2 < 2; ++n2) {
                sh8 Bf = *(const sh8*)&Bprep[
                    (size_t)(WU2B + kt * 8 + w * 2 + n2) * 512 + lane * 8];
                acc[n2] = __builtin_amdgcn_mfma_f32_16x16x32_bf16(Af, Bf, acc[n2], 0, 0, 0);
            }
        }
        if (grp == 0) {
            #pragma unroll
            for (int n2 = 0; n2 < 2; ++n2) {
                const int d = (w * 2 + n2) * 16 + lane;
                const float bb = bu2[d];
                #pragma unroll
                for (int r = 0; r < 4; ++r)
                    xsb[r * 128 + d] = up[r * 260 + d] + ftanh(acc[n2][r] + bb);
            }
        }
    }
    __syncthreads();

    {   // LayerNorm: wave w -> row w
        const float v0 = xsb[w * 128 + lane], v1 = xsb[w * 128 + lane + 64];
        float s = v0 + v1;
        #pragma unroll
        for (int m = 1; m < 64; m <<= 1) s += __shfl_xor(s, m, 64);
        const float mu = s * (1.0f / SD);
        const float d0 = v0 - mu, d1 = v1 - mu;
        float q = d0 * d0 + d1 * d1;
        #pragma unroll
        for (int m = 1; m < 64; m <<= 1) q += __shfl_xor(q, m, 64);
        const float inv = rsqrtf(q * (1.0f / SD) + 1e-5f);
        out[(size_t)(bi0 + w) * SD + lane] = d0 * inv * lnw[lane] + lnb[lane];
        out[(size_t)(bi0 + w) * SD + lane + 64] =
            d1 * inv * lnw[lane + 64] + lnb[lane + 64];
    }
}

extern "C" void kernel_launch(void* const* d_in, const int* in_sizes, int n_in,
                              void* d_out, int out_size, void* d_ws, size_t ws_size,
                              hipStream_t stream) {
    const float* h   = (const float*)d_in[0];
    const float* ef  = (const float*)d_in[1];
    const float* em  = (const float*)d_in[2];
    const float* Wm1 = (const float*)d_in[3];
    const float* bm1 = (const float*)d_in[4];
    const float* Wm2 = (const float*)d_in[5];
    const float* bm2 = (const float*)d_in[6];
    const float* Wg1 = (const float*)d_in[7];
    const float* bg1 = (const float*)d_in[8];
    const float* Wg2 = (const float*)d_in[9];
    const float* bg2 = (const float*)d_in[10];
    const float* Wu1 = (const float*)d_in[11];
    const float* bu1 = (const float*)d_in[12];
    const float* Wu2 = (const float*)d_in[13];
    const float* bu2 = (const float*)d_in[14];
    const float* lnw = (const float*)d_in[15];
    const float* lnb = (const float*)d_in[16];

    float* ws = (float*)d_ws;
    float* Hgi   = ws;
    float* Hgjt  = Hgi + (size_t)BN * ID;
    float* Hmi   = Hgjt + (size_t)BN * ID;
    float* Hmjt  = Hmi + (size_t)BN * ID;
    ushort* Bprep = (ushort*)(Hmjt + (size_t)BN * ID);
    float* outp = (float*)d_out;

    k_prep<<<544, 64, 0, stream>>>(Wg1, Wm1, Wm2, Wu1, Wu2, Bprep);
    k1_mfma<<<dim3(BN / 16, 4), 256, 0, stream>>>(h, bg1, bm1, Bprep,
                                                  Hgi, Hgjt, Hmi, Hmjt);
    k2_fused<<<BN / NI, 256, 0, stream>>>(ef, em, Bprep, Hgi, Hmi, Hgjt, Hmjt,
                                          Wg2, bg2, h, Wu1, bu1, bu2, bm2,
                                          lnw, lnb, outp);
}

// Round 13
// 149.919 us; speedup vs baseline: 1.7128x; 1.7128x over previous
//
#include <hip/hip_runtime.h>
#include <hip/hip_bf16.h>

#define BB 32
#define NN 128
#define SD 128
#define ED 32
#define ID 256
#define BN (BB*NN)   // 4096
#define NI 4         // i-blocks per k2 workgroup

// Bprep tile index bases
#define WM2B 288
#define WU1B 352
#define WU2B 480

typedef __attribute__((ext_vector_type(8))) short sh8;
typedef __attribute__((ext_vector_type(4))) float f32x4;

__device__ __forceinline__ float ftanh(float x) {
    float e2 = __expf(2.0f * x);
    return 1.0f - 2.0f * __builtin_amdgcn_rcpf(e2 + 1.0f);
}

__device__ __forceinline__ ushort f2bf(float f) {
    unsigned u = __float_as_uint(f);
    return (ushort)((u + 0x7FFF + ((u >> 16) & 1)) >> 16);
}

// build a bf16 A-frag (rows 0..3 real, 4..15 zero) from f32 LDS rows
__device__ __forceinline__ sh8 afragT(const float* base, int stride, int kt, int lane) {
    sh8 v = (sh8){0, 0, 0, 0, 0, 0, 0, 0};
    if ((lane & 15) < 4) {
        const float* p = base + (lane & 15) * stride + kt * 32 + (lane >> 4) * 8;
        f32x4 a0 = *(const f32x4*)p;
        f32x4 a1 = *(const f32x4*)(p + 4);
        v[0] = (short)f2bf(a0[0]); v[1] = (short)f2bf(a0[1]);
        v[2] = (short)f2bf(a0[2]); v[3] = (short)f2bf(a0[3]);
        v[4] = (short)f2bf(a1[0]); v[5] = (short)f2bf(a1[1]);
        v[6] = (short)f2bf(a1[2]); v[7] = (short)f2bf(a1[3]);
    }
    return v;
}

// ---------------------------------------------------------------------------
// k_prep: frag-ordered bf16 B-tiles (layout identical to R11).
// grid 544, block 64
// ---------------------------------------------------------------------------
__global__ void k_prep(const float* __restrict__ Wg1, const float* __restrict__ Wm1,
                       const float* __restrict__ Wm2, const float* __restrict__ Wu1,
                       const float* __restrict__ Wu2, ushort* __restrict__ Bprep) {
    const int tt = blockIdx.x;
    const int l = threadIdx.x;
    const float* W;
    int rowbase, nt, stride;
    if (tt < 256) {
        const int tgt = tt >> 6;
        const int kt = (tt >> 4) & 3;
        nt = tt & 15;
        W = (tgt >= 2) ? Wm1 : Wg1;
        rowbase = (tgt & 1) * 128 + kt * 32;
        stride = ID;
    } else if (tt < WM2B) {
        const int wt = tt - 256;
        W = (wt >> 4) ? Wm1 : Wg1;
        rowbase = 2 * SD;
        nt = wt & 15;
        stride = ID;
    } else if (tt < WU1B) {
        const int wt = tt - WM2B;
        W = Wm2; rowbase = (wt >> 3) * 32; nt = wt & 7; stride = SD;
    } else if (tt < WU2B) {
        const int wt = tt - WU1B;
        W = Wu1; rowbase = (wt >> 4) * 32; nt = wt & 15; stride = ID;
    } else {
        const int wt = tt - WU2B;
        W = Wu2; rowbase = (wt >> 3) * 32; nt = wt & 7; stride = SD;
    }
    const int colw = nt * 16 + (l & 15);
    const int kb = rowbase + (l >> 4) * 8;
    sh8 v;
    #pragma unroll
    for (int e = 0; e < 8; ++e)
        v[e] = (short)f2bf(W[(size_t)(kb + e) * stride + colw]);
    *(sh8*)&Bprep[(size_t)tt * 512 + l * 8] = v;
}

// ---------------------------------------------------------------------------
// K1 (MFMA): one 16-row stripe x one target per block (grid.y = tgt).
// grid (BN/16, 4), block 256
// ---------------------------------------------------------------------------
__global__ __launch_bounds__(256) void k1_mfma(
        const float* __restrict__ h,
        const float* __restrict__ bg1, const float* __restrict__ bm1,
        const ushort* __restrict__ Bprep,
        float* __restrict__ Hgi, float* __restrict__ Hgjt,
        float* __restrict__ Hmi, float* __restrict__ Hmjt) {
    const int blk = blockIdx.x;
    const int tgt = blockIdx.y;
    const int t = threadIdx.x;
    const int w = t >> 6;
    const int lane = t & 63;
    const int col = lane & 15;
    const int grp = lane >> 4;
    __shared__ __align__(16) ushort Alds[4 * 512];

    {   // stage h rows -> bf16 frag order
        const int c = t;
        const int kt = c >> 6, l = c & 63;
        const int row = l & 15;
        const int kb = kt * 32 + (l >> 4) * 8;
        const float* p = h + (size_t)(blk * 16 + row) * SD + kb;
        f32x4 a0 = *(const f32x4*)p;
        f32x4 a1 = *(const f32x4*)(p + 4);
        sh8 v;
        v[0] = (short)f2bf(a0[0]); v[1] = (short)f2bf(a0[1]);
        v[2] = (short)f2bf(a0[2]); v[3] = (short)f2bf(a0[3]);
        v[4] = (short)f2bf(a1[0]); v[5] = (short)f2bf(a1[1]);
        v[6] = (short)f2bf(a1[2]); v[7] = (short)f2bf(a1[3]);
        *(sh8*)&Alds[c * 8] = v;
    }
    __syncthreads();

    const int kcol = w * 64 + col;
    sh8 Af[4];
    #pragma unroll
    for (int kt = 0; kt < 4; ++kt)
        Af[kt] = *(const sh8*)&Alds[kt * 512 + lane * 8];

    f32x4 acc[4];
    #pragma unroll
    for (int n = 0; n < 4; ++n) acc[n] = (f32x4){0.f, 0.f, 0.f, 0.f};
    #pragma unroll
    for (int kt = 0; kt < 4; ++kt)
        #pragma unroll
        for (int n = 0; n < 4; ++n) {
            sh8 Bf = *(const sh8*)&Bprep[
                (size_t)(tgt * 64 + kt * 16 + w * 4 + n) * 512 + lane * 8];
            acc[n] = __builtin_amdgcn_mfma_f32_16x16x32_bf16(
                Af[kt], Bf, acc[n], 0, 0, 0);
        }
    if (tgt & 1) {
        float* out = (tgt == 1) ? Hgjt : Hmjt;
        #pragma unroll
        for (int n = 0; n < 4; ++n)
            *(f32x4*)&out[((size_t)blk * ID + kcol + n * 16) * 16 + grp * 4] = acc[n];
    } else {
        const float* bias = (tgt == 0) ? bg1 : bm1;
        float* out = (tgt == 0) ? Hgi : Hmi;
        #pragma unroll
        for (int n = 0; n < 4; ++n) {
            const float bv = bias[kcol + n * 16];
            #pragma unroll
            for (int r = 0; r < 4; ++r)
                out[(size_t)(blk * 16 + grp * 4 + r) * ID + kcol + n * 16] =
                    acc[n][r] + bv;
        }
    }
}

// ---------------------------------------------------------------------------
// K2 fused, j-halved: per half {stage 16KB E, gate, sigmoid, msg}. LDS ~18.9KB
// + VGPR 64 -> up to 8 blocks/CU resident (bounds (256,4): allocator relaxed,
// residency set by resources -- R12's (256,8) forced VGPR 32 and spilled).
// grid BN/NI, block 256
// ---------------------------------------------------------------------------
__global__ __launch_bounds__(256, 4) void k2_fused(
        const float* __restrict__ ef, const float* __restrict__ em,
        const ushort* __restrict__ Bprep,
        const float* __restrict__ Hgi, const float* __restrict__ Hmi,
        const float* __restrict__ Hgjt, const float* __restrict__ Hmjt,
        const float* __restrict__ Wg2, const float* __restrict__ bg2,
        const float* __restrict__ h,
        const float* __restrict__ Wu1, const float* __restrict__ bu1,
        const float* __restrict__ bu2, const float* __restrict__ bm2,
        const float* __restrict__ lnw, const float* __restrict__ lnb,
        float* __restrict__ out) {
    const int bi0 = blockIdx.x * NI;
    const int b = bi0 >> 7;
    const int t = threadIdx.x;
    const int w = t >> 6;
    const int lane = t & 63;
    const int col = lane & 15;
    const int grp = lane >> 4;

    __shared__ __align__(16) ushort Elds[NI * 4 * 512];   // 16 KB
    __shared__ float glds[NI][NN];                        // 2 KB
    __shared__ float gsumL[NI], degL[NI];

    {
        float* gl = &glds[0][0];
        gl[t] = 0.f;
        gl[t + 256] = 0.f;
    }

    const int kcol = w * 64 + col;
    const float* HgjL = Hgjt + (size_t)b * 8 * ID * 16 + (size_t)kcol * 16 + grp * 4;
    const float* HmjL = Hmjt + (size_t)b * 8 * ID * 16 + (size_t)kcol * 16 + grp * 4;
    const float bg2v = bg2[0];

    float ts[NI][4];
    #pragma unroll
    for (int i = 0; i < NI; ++i)
        #pragma unroll
        for (int n = 0; n < 4; ++n) ts[i][n] = 0.f;
    float gs_run = 0.f, dv_run = 0.f;

    for (int half = 0; half < 2; ++half) {
        __syncthreads();   // protect Elds from previous half's msg readers
        // ---- stage E for this half (frag-ordered, conflict-free)
        #pragma unroll
        for (int i = 0; i < NI; ++i) {
            const float* efb = ef + (size_t)(bi0 + i) * NN * ED;
            const int c = t;                               // chunk 0..255
            const int j = (half * 4 + (c >> 6)) * 16 + (c & 15);
            const int kb = ((c >> 4) & 3) * 8;
            const float* p = efb + j * ED + kb;
            f32x4 a0 = *(const f32x4*)p;
            f32x4 a1 = *(const f32x4*)(p + 4);
            sh8 v;
            v[0] = (short)f2bf(a0[0]); v[1] = (short)f2bf(a0[1]);
            v[2] = (short)f2bf(a0[2]); v[3] = (short)f2bf(a0[3]);
            v[4] = (short)f2bf(a1[0]); v[5] = (short)f2bf(a1[1]);
            v[6] = (short)f2bf(a1[2]); v[7] = (short)f2bf(a1[3]);
            *(sh8*)&Elds[i * 2048 + c * 8] = v;
        }
        __syncthreads();

        // ================= gate pass (4 s-tiles of this half)
        {
            sh8 Bg[4];
            float hgiR[NI][4], wg2R[4];
            #pragma unroll
            for (int n = 0; n < 4; ++n) {
                Bg[n] = *(const sh8*)&Bprep[(size_t)(256 + w * 4 + n) * 512 + lane * 8];
                wg2R[n] = Wg2[kcol + n * 16];
            }
            #pragma unroll
            for (int i = 0; i < NI; ++i)
                #pragma unroll
                for (int n = 0; n < 4; ++n)
                    hgiR[i][n] = Hgi[(size_t)(bi0 + i) * ID + kcol + n * 16];
            const float* Hbase = HgjL + (size_t)(half * 4) * (ID * 16);
            f32x4 Cg[4], Cn[4];
            #pragma unroll
            for (int n = 0; n < 4; ++n) Cg[n] = *(const f32x4*)(Hbase + n * 256);
            for (int st = 0; st < 4; ++st) {
                if (st < 3) {
                    const float* ps = Hbase + (size_t)(st + 1) * (ID * 16);
                    #pragma unroll
                    for (int n = 0; n < 4; ++n) Cn[n] = *(const f32x4*)(ps + n * 256);
                }
                #pragma unroll
                for (int i = 0; i < NI; ++i) {
                    sh8 Af = *(const sh8*)&Elds[i * 2048 + st * 512 + lane * 8];
                    f32x4 acc[4];
                    #pragma unroll
                    for (int n = 0; n < 4; ++n)
                        acc[n] = __builtin_amdgcn_mfma_f32_16x16x32_bf16(
                            Af, Bg[n], Cg[n], 0, 0, 0);
                    float p[4] = {0.f, 0.f, 0.f, 0.f};
                    #pragma unroll
                    for (int n = 0; n < 4; ++n)
                        #pragma unroll
                        for (int r = 0; r < 4; ++r)
                            p[r] = fmaf(ftanh(acc[n][r] + hgiR[i][n]), wg2R[n], p[r]);
                    #pragma unroll
                    for (int m = 1; m < 16; m <<= 1)
                        #pragma unroll
                        for (int r = 0; r < 4; ++r) p[r] += __shfl_xor(p[r], m, 64);
                    if (col == 0) {
                        #pragma unroll
                        for (int r = 0; r < 4; ++r)
                            atomicAdd(&glds[i][(half * 4 + st) * 16 + grp * 4 + r],
                                      p[r]);
                    }
                }
                #pragma unroll
                for (int n = 0; n < 4; ++n) Cg[n] = Cn[n];
            }
        }
        __syncthreads();

        // ---- sigmoid + mask for this half's j (wave w -> i=w)
        {
            const int j = half * 64 + lane;
            const float pre = glds[w][j] + bg2v;
            const float m = em[(size_t)(bi0 + w) * NN + j];
            const float g = m * __builtin_amdgcn_rcpf(1.0f + __expf(-pre));
            glds[w][j] = g;
            gs_run += g;
            dv_run += m;
        }
        __syncthreads();

        // ================= msg pass (4 s-tiles of this half)
        {
            sh8 Bm[4];
            float hmiR[NI][4];
            #pragma unroll
            for (int n = 0; n < 4; ++n)
                Bm[n] = *(const sh8*)&Bprep[(size_t)(272 + w * 4 + n) * 512 + lane * 8];
            #pragma unroll
            for (int i = 0; i < NI; ++i)
                #pragma unroll
                for (int n = 0; n < 4; ++n)
                    hmiR[i][n] = Hmi[(size_t)(bi0 + i) * ID + kcol + n * 16];
            const float* Hbase = HmjL + (size_t)(half * 4) * (ID * 16);
            f32x4 Cm[4], Cn[4];
            #pragma unroll
            for (int n = 0; n < 4; ++n) Cm[n] = *(const f32x4*)(Hbase + n * 256);
            for (int st = 0; st < 4; ++st) {
                if (st < 3) {
                    const float* ps = Hbase + (size_t)(st + 1) * (ID * 16);
                    #pragma unroll
                    for (int n = 0; n < 4; ++n) Cn[n] = *(const f32x4*)(ps + n * 256);
                }
                #pragma unroll
                for (int i = 0; i < NI; ++i) {
                    sh8 Af = *(const sh8*)&Elds[i * 2048 + st * 512 + lane * 8];
                    f32x4 acc[4];
                    #pragma unroll
                    for (int n = 0; n < 4; ++n)
                        acc[n] = __builtin_amdgcn_mfma_f32_16x16x32_bf16(
                            Af, Bm[n], Cm[n], 0, 0, 0);
                    f32x4 gr = *(const f32x4*)&glds[i][(half * 4 + st) * 16 + grp * 4];
                    #pragma unroll
                    for (int n = 0; n < 4; ++n)
                        #pragma unroll
                        for (int r = 0; r < 4; ++r)
                            ts[i][n] = fmaf(gr[r], ftanh(acc[n][r] + hmiR[i][n]),
                                            ts[i][n]);
                }
                #pragma unroll
                for (int n = 0; n < 4; ++n) Cm[n] = Cn[n];
            }
        }
    }

    // ---- final gsum/deg reduce (wave w owns i=w)
    #pragma unroll
    for (int mm = 1; mm < 64; mm <<= 1) {
        gs_run += __shfl_xor(gs_run, mm, 64);
        dv_run += __shfl_xor(dv_run, mm, 64);
    }
    if (lane == 0) { gsumL[w] = gs_run; degL[w] = dv_run; }

    // ---- ts k-reduce
    #pragma unroll
    for (int i = 0; i < NI; ++i)
        #pragma unroll
        for (int n = 0; n < 4; ++n) {
            ts[i][n] += __shfl_xor(ts[i][n], 16, 64);
            ts[i][n] += __shfl_xor(ts[i][n], 32, 64);
        }

    // ================= MFMA tail (reuse Elds as f32 scratch)
    __syncthreads();                      // Elds reads done; gsumL/degL visible
    float* scratch = (float*)Elds;
    float* Tl  = scratch;                 // [4][256]
    float* up  = scratch + 1024;          // [4][260]
    float* uu  = scratch + 2064;          // [4][256] -- total 16.4KB > 16KB Elds,
    float* xsb = scratch + 3088;          //   spills into glds region (dead by now)
    if (lane < 16) {
        #pragma unroll
        for (int i = 0; i < NI; ++i)
            #pragma unroll
            for (int n = 0; n < 4; ++n)
                Tl[i * 256 + w * 64 + n * 16 + lane] = ts[i][n];
    }
    #pragma unroll
    for (int it = 0; it < 2; ++it) {
        const int idx = it * 256 + t;
        const int i = idx >> 7, c = idx & 127;
        up[i * 260 + c] = h[(size_t)(bi0 + i) * SD + c];
    }
    if (t < NI) up[t * 260 + 256] = degL[t] * (1.0f / 127.0f);
    __syncthreads();

    {   // agg: up[i][128+d] = (T@Wm2 + g*bm2)/max(g,1); wave w -> nt {2w,2w+1}
        f32x4 acc[2];
        acc[0] = (f32x4){0.f, 0.f, 0.f, 0.f};
        acc[1] = (f32x4){0.f, 0.f, 0.f, 0.f};
        #pragma unroll
        for (int kt = 0; kt < 8; ++kt) {
            sh8 Af = afragT(Tl, 256, kt, lane);
            #pragma unroll
            for (int n2 = 0; n2 < 2; ++n2) {
                sh8 Bf = *(const sh8*)&Bprep[
                    (size_t)(WM2B + kt * 8 + w * 2 + n2) * 512 + lane * 8];
                acc[n2] = __builtin_amdgcn_mfma_f32_16x16x32_bf16(Af, Bf, acc[n2], 0, 0, 0);
            }
        }
        if (grp == 0) {
            #pragma unroll
            for (int n2 = 0; n2 < 2; ++n2) {
                const int d = (w * 2 + n2) * 16 + lane;
                const float bmv = bm2[d];
                #pragma unroll
                for (int r = 0; r < 4; ++r) {
                    const float g = gsumL[r];
                    up[r * 260 + SD + d] = fmaf(g, bmv, acc[n2][r]) *
                                           __builtin_amdgcn_rcpf(fmaxf(g, 1.0f));
                }
            }
        }
    }
    __syncthreads();

    {   // FC1: uu = tanh(up@Wu1 + bu1 + deg-row); wave w -> nt {4w..4w+3}
        f32x4 acc[4];
        #pragma unroll
        for (int n2 = 0; n2 < 4; ++n2) acc[n2] = (f32x4){0.f, 0.f, 0.f, 0.f};
        #pragma unroll
        for (int kt = 0; kt < 8; ++kt) {
            sh8 Af = afragT(up, 260, kt, lane);
            #pragma unroll
            for (int n2 = 0; n2 < 4; ++n2) {
                sh8 Bf = *(const sh8*)&Bprep[
                    (size_t)(WU1B + kt * 16 + w * 4 + n2) * 512 + lane * 8];
                acc[n2] = __builtin_amdgcn_mfma_f32_16x16x32_bf16(Af, Bf, acc[n2], 0, 0, 0);
            }
        }
        if (grp == 0) {
            #pragma unroll
            for (int n2 = 0; n2 < 4; ++n2) {
                const int kc = (w * 4 + n2) * 16 + lane;
                const float wdeg = Wu1[(size_t)(2 * SD) * ID + kc];
                const float bb = bu1[kc];
                #pragma unroll
                for (int r = 0; r < 4; ++r)
                    uu[r * 256 + kc] =
                        ftanh(acc[n2][r] + bb + up[r * 260 + 256] * wdeg);
            }
        }
    }
    __syncthreads();

    {   // FC2 + residual: xs = h + tanh(uu@Wu2 + bu2); wave w -> nt {2w,2w+1}
        f32x4 acc[2];
        acc[0] = (f32x4){0.f, 0.f, 0.f, 0.f};
        acc[1] = (f32x4){0.f, 0.f, 0.f, 0.f};
        #pragma unroll
        for (int kt = 0; kt < 8; ++kt) {
            sh8 Af = afragT(uu, 256, kt, lane);
            #pragma unroll
            for (int n2 = 0; n2 < 2; ++n2) {
                sh8 Bf = *(const sh8*)&Bprep[
                    (size_t)(WU2B + kt * 8 + w * 2 + n2) * 512 + lane * 8];
                acc[n2] = __builtin_amdgcn_mfma_f32_16x16x32_bf16(Af, Bf, acc[n2], 0, 0, 0);
            }
        }
        if (grp == 0) {
            #pragma unroll
            for (int n2 = 0; n2 < 2; ++n2) {
                const int d = (w * 2 + n2) * 16 + lane;
                const float bb = bu2[d];
                #pragma unroll
                for (int r = 0; r < 4; ++r)
                    xsb[r * 128 + d] = up[r * 260 + d] + ftanh(acc[n2][r] + bb);
            }
        }
    }
    __syncthreads();

    {   // LayerNorm: wave w -> row w
        const float v0 = xsb[w * 128 + lane], v1 = xsb[w * 128 + lane + 64];
        float s = v0 + v1;
        #pragma unroll
        for (int m = 1; m < 64; m <<= 1) s += __shfl_xor(s, m, 64);
        const float mu = s * (1.0f / SD);
        const float d0 = v0 - mu, d1 = v1 - mu;
        float q = d0 * d0 + d1 * d1;
        #pragma unroll
        for (int m = 1; m < 64; m <<= 1) q += __shfl_xor(q, m, 64);
        const float inv = rsqrtf(q * (1.0f / SD) + 1e-5f);
        out[(size_t)(bi0 + w) * SD + lane] = d0 * inv * lnw[lane] + lnb[lane];
        out[(size_t)(bi0 + w) * SD + lane + 64] =
            d1 * inv * lnw[lane + 64] + lnb[lane + 64];
    }
}

extern "C" void kernel_launch(void* const* d_in, const int* in_sizes, int n_in,
                              void* d_out, int out_size, void* d_ws, size_t ws_size,
                              hipStream_t stream) {
    const float* h   = (const float*)d_in[0];
    const float* ef  = (const float*)d_in[1];
    const float* em  = (const float*)d_in[2];
    const float* Wm1 = (const float*)d_in[3];
    const float* bm1 = (const float*)d_in[4];
    const float* Wm2 = (const float*)d_in[5];
    const float* bm2 = (const float*)d_in[6];
    const float* Wg1 = (const float*)d_in[7];
    const float* bg1 = (const float*)d_in[8];
    const float* Wg2 = (const float*)d_in[9];
    const float* bg2 = (const float*)d_in[10];
    const float* Wu1 = (const float*)d_in[11];
    const float* bu1 = (const float*)d_in[12];
    const float* Wu2 = (const float*)d_in[13];
    const float* bu2 = (const float*)d_in[14];
    const float* lnw = (const float*)d_in[15];
    const float* lnb = (const float*)d_in[16];

    float* ws = (float*)d_ws;
    float* Hgi   = ws;
    float* Hgjt  = Hgi + (size_t)BN * ID;
    float* Hmi   = Hgjt + (size_t)BN * ID;
    float* Hmjt  = Hmi + (size_t)BN * ID;
    ushort* Bprep = (ushort*)(Hmjt + (size_t)BN * ID);
    float* outp = (float*)d_out;

    k_prep<<<544, 64, 0, stream>>>(Wg1, Wm1, Wm2, Wu1, Wu2, Bprep);
    k1_mfma<<<dim3(BN / 16, 4), 256, 0, stream>>>(h, bg1, bm1, Bprep,
                                                  Hgi, Hgjt, Hmi, Hmjt);
    k2_fused<<<BN / NI, 256, 0, stream>>>(ef, em, Bprep, Hgi, Hmi, Hgjt, Hmjt,
                                          Wg2, bg2, h, Wu1, bu1, bu2, bm2,
                                          lnw, lnb, outp);
}

// Round 14
// 124.020 us; speedup vs baseline: 2.0705x; 1.2088x over previous
//
#include <hip/hip_runtime.h>
#include <hip/hip_bf16.h>

#define BB 32
#define NN 128
#define SD 128
#define ED 32
#define ID 256
#define BN (BB*NN)   // 4096
#define NI 4         // i-blocks per k2 workgroup

// Bprep tile index bases
#define WM2B 288
#define WU1B 352
#define WU2B 480

typedef __attribute__((ext_vector_type(8))) short sh8;
typedef __attribute__((ext_vector_type(4))) float f32x4;

__device__ __forceinline__ float ftanh(float x) {
    float e2 = __expf(2.0f * x);
    return 1.0f - 2.0f * __builtin_amdgcn_rcpf(e2 + 1.0f);
}

__device__ __forceinline__ ushort f2bf(float f) {
    unsigned u = __float_as_uint(f);
    return (ushort)((u + 0x7FFF + ((u >> 16) & 1)) >> 16);
}

// build a bf16 A-frag (rows 0..3 real, 4..15 zero) from f32 LDS rows
__device__ __forceinline__ sh8 afragT(const float* base, int stride, int kt, int lane) {
    sh8 v = (sh8){0, 0, 0, 0, 0, 0, 0, 0};
    if ((lane & 15) < 4) {
        const float* p = base + (lane & 15) * stride + kt * 32 + (lane >> 4) * 8;
        f32x4 a0 = *(const f32x4*)p;
        f32x4 a1 = *(const f32x4*)(p + 4);
        v[0] = (short)f2bf(a0[0]); v[1] = (short)f2bf(a0[1]);
        v[2] = (short)f2bf(a0[2]); v[3] = (short)f2bf(a0[3]);
        v[4] = (short)f2bf(a1[0]); v[5] = (short)f2bf(a1[1]);
        v[6] = (short)f2bf(a1[2]); v[7] = (short)f2bf(a1[3]);
    }
    return v;
}

// ---------------------------------------------------------------------------
// k_prep: frag-ordered bf16 B-tiles (layout identical to R11).
// grid 544, block 64
// ---------------------------------------------------------------------------
__global__ void k_prep(const float* __restrict__ Wg1, const float* __restrict__ Wm1,
                       const float* __restrict__ Wm2, const float* __restrict__ Wu1,
                       const float* __restrict__ Wu2, ushort* __restrict__ Bprep) {
    const int tt = blockIdx.x;
    const int l = threadIdx.x;
    const float* W;
    int rowbase, nt, stride;
    if (tt < 256) {
        const int tgt = tt >> 6;
        const int kt = (tt >> 4) & 3;
        nt = tt & 15;
        W = (tgt >= 2) ? Wm1 : Wg1;
        rowbase = (tgt & 1) * 128 + kt * 32;
        stride = ID;
    } else if (tt < WM2B) {
        const int wt = tt - 256;
        W = (wt >> 4) ? Wm1 : Wg1;
        rowbase = 2 * SD;
        nt = wt & 15;
        stride = ID;
    } else if (tt < WU1B) {
        const int wt = tt - WM2B;
        W = Wm2; rowbase = (wt >> 3) * 32; nt = wt & 7; stride = SD;
    } else if (tt < WU2B) {
        const int wt = tt - WU1B;
        W = Wu1; rowbase = (wt >> 4) * 32; nt = wt & 15; stride = ID;
    } else {
        const int wt = tt - WU2B;
        W = Wu2; rowbase = (wt >> 3) * 32; nt = wt & 7; stride = SD;
    }
    const int colw = nt * 16 + (l & 15);
    const int kb = rowbase + (l >> 4) * 8;
    sh8 v;
    #pragma unroll
    for (int e = 0; e < 8; ++e)
        v[e] = (short)f2bf(W[(size_t)(kb + e) * stride + colw]);
    *(sh8*)&Bprep[(size_t)tt * 512 + l * 8] = v;
}

// ---------------------------------------------------------------------------
// K1 (MFMA): one 16-row stripe x one target per block (grid.y = tgt).
// grid (BN/16, 4), block 256
// ---------------------------------------------------------------------------
__global__ __launch_bounds__(256) void k1_mfma(
        const float* __restrict__ h,
        const float* __restrict__ bg1, const float* __restrict__ bm1,
        const ushort* __restrict__ Bprep,
        float* __restrict__ Hgi, float* __restrict__ Hgjt,
        float* __restrict__ Hmi, float* __restrict__ Hmjt) {
    const int blk = blockIdx.x;
    const int tgt = blockIdx.y;
    const int t = threadIdx.x;
    const int w = t >> 6;
    const int lane = t & 63;
    const int col = lane & 15;
    const int grp = lane >> 4;
    __shared__ __align__(16) ushort Alds[4 * 512];

    {   // stage h rows -> bf16 frag order
        const int c = t;
        const int kt = c >> 6, l = c & 63;
        const int row = l & 15;
        const int kb = kt * 32 + (l >> 4) * 8;
        const float* p = h + (size_t)(blk * 16 + row) * SD + kb;
        f32x4 a0 = *(const f32x4*)p;
        f32x4 a1 = *(const f32x4*)(p + 4);
        sh8 v;
        v[0] = (short)f2bf(a0[0]); v[1] = (short)f2bf(a0[1]);
        v[2] = (short)f2bf(a0[2]); v[3] = (short)f2bf(a0[3]);
        v[4] = (short)f2bf(a1[0]); v[5] = (short)f2bf(a1[1]);
        v[6] = (short)f2bf(a1[2]); v[7] = (short)f2bf(a1[3]);
        *(sh8*)&Alds[c * 8] = v;
    }
    __syncthreads();

    const int kcol = w * 64 + col;
    sh8 Af[4];
    #pragma unroll
    for (int kt = 0; kt < 4; ++kt)
        Af[kt] = *(const sh8*)&Alds[kt * 512 + lane * 8];

    f32x4 acc[4];
    #pragma unroll
    for (int n = 0; n < 4; ++n) acc[n] = (f32x4){0.f, 0.f, 0.f, 0.f};
    #pragma unroll
    for (int kt = 0; kt < 4; ++kt)
        #pragma unroll
        for (int n = 0; n < 4; ++n) {
            sh8 Bf = *(const sh8*)&Bprep[
                (size_t)(tgt * 64 + kt * 16 + w * 4 + n) * 512 + lane * 8];
            acc[n] = __builtin_amdgcn_mfma_f32_16x16x32_bf16(
                Af[kt], Bf, acc[n], 0, 0, 0);
        }
    if (tgt & 1) {
        float* out = (tgt == 1) ? Hgjt : Hmjt;
        #pragma unroll
        for (int n = 0; n < 4; ++n)
            *(f32x4*)&out[((size_t)blk * ID + kcol + n * 16) * 16 + grp * 4] = acc[n];
    } else {
        const float* bias = (tgt == 0) ? bg1 : bm1;
        float* out = (tgt == 0) ? Hgi : Hmi;
        #pragma unroll
        for (int n = 0; n < 4; ++n) {
            const float bv = bias[kcol + n * 16];
            #pragma unroll
            for (int r = 0; r < 4; ++r)
                out[(size_t)(blk * 16 + grp * 4 + r) * ID + kcol + n * 16] =
                    acc[n][r] + bv;
        }
    }
}

// ---------------------------------------------------------------------------
// K2 fused: R11 pass ORDER (gate all-j, sigmoid, msg all-j) with 16KB Elds,
// E staged twice (once per pass, 2 halves each). No register lives across a
// staging boundary that didn't in R11 -> no spill; LDS ~18.6KB -> 8 blk/CU.
// grid BN/NI, block 256
// ---------------------------------------------------------------------------
__global__ __launch_bounds__(256, 4) void k2_fused(
        const float* __restrict__ ef, const float* __restrict__ em,
        const ushort* __restrict__ Bprep,
        const float* __restrict__ Hgi, const float* __restrict__ Hmi,
        const float* __restrict__ Hgjt, const float* __restrict__ Hmjt,
        const float* __restrict__ Wg2, const float* __restrict__ bg2,
        const float* __restrict__ h,
        const float* __restrict__ Wu1, const float* __restrict__ bu1,
        const float* __restrict__ bu2, const float* __restrict__ bm2,
        const float* __restrict__ lnw, const float* __restrict__ lnb,
        float* __restrict__ out) {
    const int bi0 = blockIdx.x * NI;
    const int b = bi0 >> 7;
    const int t = threadIdx.x;
    const int w = t >> 6;
    const int lane = t & 63;
    const int col = lane & 15;
    const int grp = lane >> 4;

    __shared__ __align__(16) ushort Elds[NI * 4 * 512];   // 16 KB
    __shared__ float glds[NI][NN];                        // 2 KB
    __shared__ float red[2][4][2];
    __shared__ float gsumL[NI], degL[NI];

    {
        float* gl = &glds[0][0];
        gl[t] = 0.f;
        gl[t + 256] = 0.f;
    }

    const int kcol = w * 64 + col;
    const float* HgjL = Hgjt + (size_t)b * 8 * ID * 16 + (size_t)kcol * 16 + grp * 4;
    const float* HmjL = Hmjt + (size_t)b * 8 * ID * 16 + (size_t)kcol * 16 + grp * 4;

    // ================= gate pass (2 halves; stage then 4 s-tiles each)
    for (int half = 0; half < 2; ++half) {
        __syncthreads();   // prior Elds readers done (iter0: after glds zero)
        #pragma unroll
        for (int i = 0; i < NI; ++i) {
            const float* efb = ef + (size_t)(bi0 + i) * NN * ED;
            const int c = t;                               // chunk 0..255
            const int j = (half * 4 + (c >> 6)) * 16 + (c & 15);
            const int kb = ((c >> 4) & 3) * 8;
            const float* p = efb + j * ED + kb;
            f32x4 a0 = *(const f32x4*)p;
            f32x4 a1 = *(const f32x4*)(p + 4);
            sh8 v;
            v[0] = (short)f2bf(a0[0]); v[1] = (short)f2bf(a0[1]);
            v[2] = (short)f2bf(a0[2]); v[3] = (short)f2bf(a0[3]);
            v[4] = (short)f2bf(a1[0]); v[5] = (short)f2bf(a1[1]);
            v[6] = (short)f2bf(a1[2]); v[7] = (short)f2bf(a1[3]);
            *(sh8*)&Elds[i * 2048 + c * 8] = v;
        }
        __syncthreads();

        sh8 Bg[4];
        float hgiR[NI][4], wg2R[4];
        #pragma unroll
        for (int n = 0; n < 4; ++n) {
            Bg[n] = *(const sh8*)&Bprep[(size_t)(256 + w * 4 + n) * 512 + lane * 8];
            wg2R[n] = Wg2[kcol + n * 16];
        }
        #pragma unroll
        for (int i = 0; i < NI; ++i)
            #pragma unroll
            for (int n = 0; n < 4; ++n)
                hgiR[i][n] = Hgi[(size_t)(bi0 + i) * ID + kcol + n * 16];
        const float* Hbase = HgjL + (size_t)(half * 4) * (ID * 16);
        f32x4 Cg[4], Cn[4];
        #pragma unroll
        for (int n = 0; n < 4; ++n) Cg[n] = *(const f32x4*)(Hbase + n * 256);
        for (int st = 0; st < 4; ++st) {
            if (st < 3) {
                const float* ps = Hbase + (size_t)(st + 1) * (ID * 16);
                #pragma unroll
                for (int n = 0; n < 4; ++n) Cn[n] = *(const f32x4*)(ps + n * 256);
            }
            #pragma unroll
            for (int i = 0; i < NI; ++i) {
                sh8 Af = *(const sh8*)&Elds[i * 2048 + st * 512 + lane * 8];
                f32x4 acc[4];
                #pragma unroll
                for (int n = 0; n < 4; ++n)
                    acc[n] = __builtin_amdgcn_mfma_f32_16x16x32_bf16(
                        Af, Bg[n], Cg[n], 0, 0, 0);
                float p[4] = {0.f, 0.f, 0.f, 0.f};
                #pragma unroll
                for (int n = 0; n < 4; ++n)
                    #pragma unroll
                    for (int r = 0; r < 4; ++r)
                        p[r] = fmaf(ftanh(acc[n][r] + hgiR[i][n]), wg2R[n], p[r]);
                #pragma unroll
                for (int m = 1; m < 16; m <<= 1)
                    #pragma unroll
                    for (int r = 0; r < 4; ++r) p[r] += __shfl_xor(p[r], m, 64);
                if (col == 0) {
                    #pragma unroll
                    for (int r = 0; r < 4; ++r)
                        atomicAdd(&glds[i][(half * 4 + st) * 16 + grp * 4 + r],
                                  p[r]);
                }
            }
            #pragma unroll
            for (int n = 0; n < 4; ++n) Cg[n] = Cn[n];
        }
    }
    __syncthreads();

    // ---- sigmoid + mask, gsum/deg reductions (R11 form)
    {
        const float bg2v = bg2[0];
        #pragma unroll
        for (int it = 0; it < NI / 2; ++it) {
            const int i = it * 2 + (t >> 7);
            const int j = t & 127;
            const float pre = glds[i][j] + bg2v;
            const float m = em[(size_t)(bi0 + i) * NN + j];
            const float g = m * __builtin_amdgcn_rcpf(1.0f + __expf(-pre));
            glds[i][j] = g;
            float gsv = g, dv = m;
            #pragma unroll
            for (int mm = 1; mm < 64; mm <<= 1) {
                gsv += __shfl_xor(gsv, mm, 64);
                dv  += __shfl_xor(dv, mm, 64);
            }
            if (lane == 0) { red[it][w][0] = gsv; red[it][w][1] = dv; }
        }
    }
    __syncthreads();
    if (t < NI) {
        const int it = t >> 1, w0 = (t & 1) * 2;
        gsumL[t] = red[it][w0][0] + red[it][w0 + 1][0];
        degL[t]  = red[it][w0][1] + red[it][w0 + 1][1];
    }

    // ================= msg pass (2 halves; stage then 4 s-tiles each)
    float ts[NI][4];
    #pragma unroll
    for (int i = 0; i < NI; ++i)
        #pragma unroll
        for (int n = 0; n < 4; ++n) ts[i][n] = 0.f;
    for (int half = 0; half < 2; ++half) {
        __syncthreads();   // prior Elds readers (gate/sigmoid barriers cover h=0)
        #pragma unroll
        for (int i = 0; i < NI; ++i) {
            const float* efb = ef + (size_t)(bi0 + i) * NN * ED;
            const int c = t;
            const int j = (half * 4 + (c >> 6)) * 16 + (c & 15);
            const int kb = ((c >> 4) & 3) * 8;
            const float* p = efb + j * ED + kb;
            f32x4 a0 = *(const f32x4*)p;
            f32x4 a1 = *(const f32x4*)(p + 4);
            sh8 v;
            v[0] = (short)f2bf(a0[0]); v[1] = (short)f2bf(a0[1]);
            v[2] = (short)f2bf(a0[2]); v[3] = (short)f2bf(a0[3]);
            v[4] = (short)f2bf(a1[0]); v[5] = (short)f2bf(a1[1]);
            v[6] = (short)f2bf(a1[2]); v[7] = (short)f2bf(a1[3]);
            *(sh8*)&Elds[i * 2048 + c * 8] = v;
        }
        __syncthreads();

        sh8 Bm[4];
        float hmiR[NI][4];
        #pragma unroll
        for (int n = 0; n < 4; ++n)
            Bm[n] = *(const sh8*)&Bprep[(size_t)(272 + w * 4 + n) * 512 + lane * 8];
        #pragma unroll
        for (int i = 0; i < NI; ++i)
            #pragma unroll
            for (int n = 0; n < 4; ++n)
                hmiR[i][n] = Hmi[(size_t)(bi0 + i) * ID + kcol + n * 16];
        const float* Hbase = HmjL + (size_t)(half * 4) * (ID * 16);
        f32x4 Cm[4], Cn[4];
        #pragma unroll
        for (int n = 0; n < 4; ++n) Cm[n] = *(const f32x4*)(Hbase + n * 256);
        for (int st = 0; st < 4; ++st) {
            if (st < 3) {
                const float* ps = Hbase + (size_t)(st + 1) * (ID * 16);
                #pragma unroll
                for (int n = 0; n < 4; ++n) Cn[n] = *(const f32x4*)(ps + n * 256);
            }
            #pragma unroll
            for (int i = 0; i < NI; ++i) {
                sh8 Af = *(const sh8*)&Elds[i * 2048 + st * 512 + lane * 8];
                f32x4 acc[4];
                #pragma unroll
                for (int n = 0; n < 4; ++n)
                    acc[n] = __builtin_amdgcn_mfma_f32_16x16x32_bf16(
                        Af, Bm[n], Cm[n], 0, 0, 0);
                f32x4 gr = *(const f32x4*)&glds[i][(half * 4 + st) * 16 + grp * 4];
                #pragma unroll
                for (int n = 0; n < 4; ++n)
                    #pragma unroll
                    for (int r = 0; r < 4; ++r)
                        ts[i][n] = fmaf(gr[r], ftanh(acc[n][r] + hmiR[i][n]),
                                        ts[i][n]);
            }
            #pragma unroll
            for (int n = 0; n < 4; ++n) Cm[n] = Cn[n];
        }
    }
    #pragma unroll
    for (int i = 0; i < NI; ++i)
        #pragma unroll
        for (int n = 0; n < 4; ++n) {
            ts[i][n] += __shfl_xor(ts[i][n], 16, 64);
            ts[i][n] += __shfl_xor(ts[i][n], 32, 64);
        }

    // ================= MFMA tail (reuse Elds as f32 scratch; 14.4KB < 16KB)
    __syncthreads();
    float* scratch = (float*)Elds;
    float* Tl  = scratch;                 // [4][256]
    float* up  = scratch + 1024;          // [4][260]
    float* uu  = scratch + 2064;          // [4][256]
    float* xsb = scratch + 3088;          // [4][128]
    if (lane < 16) {
        #pragma unroll
        for (int i = 0; i < NI; ++i)
            #pragma unroll
            for (int n = 0; n < 4; ++n)
                Tl[i * 256 + w * 64 + n * 16 + lane] = ts[i][n];
    }
    #pragma unroll
    for (int it = 0; it < 2; ++it) {
        const int idx = it * 256 + t;
        const int i = idx >> 7, c = idx & 127;
        up[i * 260 + c] = h[(size_t)(bi0 + i) * SD + c];
    }
    if (t < NI) up[t * 260 + 256] = degL[t] * (1.0f / 127.0f);
    __syncthreads();

    {   // agg: up[i][128+d] = (T@Wm2 + g*bm2)/max(g,1); wave w -> nt {2w,2w+1}
        f32x4 acc[2];
        acc[0] = (f32x4){0.f, 0.f, 0.f, 0.f};
        acc[1] = (f32x4){0.f, 0.f, 0.f, 0.f};
        #pragma unroll
        for (int kt = 0; kt < 8; ++kt) {
            sh8 Af = afragT(Tl, 256, kt, lane);
            #pragma unroll
            for (int n2 = 0; n2 < 2; ++n2) {
                sh8 Bf = *(const sh8*)&Bprep[
                    (size_t)(WM2B + kt * 8 + w * 2 + n2) * 512 + lane * 8];
                acc[n2] = __builtin_amdgcn_mfma_f32_16x16x32_bf16(Af, Bf, acc[n2], 0, 0, 0);
            }
        }
        if (grp == 0) {
            #pragma unroll
            for (int n2 = 0; n2 < 2; ++n2) {
                const int d = (w * 2 + n2) * 16 + lane;
                const float bmv = bm2[d];
                #pragma unroll
                for (int r = 0; r < 4; ++r) {
                    const float g = gsumL[r];
                    up[r * 260 + SD + d] = fmaf(g, bmv, acc[n2][r]) *
                                           __builtin_amdgcn_rcpf(fmaxf(g, 1.0f));
                }
            }
        }
    }
    __syncthreads();

    {   // FC1: uu = tanh(up@Wu1 + bu1 + deg-row); wave w -> nt {4w..4w+3}
        f32x4 acc[4];
        #pragma unroll
        for (int n2 = 0; n2 < 4; ++n2) acc[n2] = (f32x4){0.f, 0.f, 0.f, 0.f};
        #pragma unroll
        for (int kt = 0; kt < 8; ++kt) {
            sh8 Af = afragT(up, 260, kt, lane);
            #pragma unroll
            for (int n2 = 0; n2 < 4; ++n2) {
                sh8 Bf = *(const sh8*)&Bprep[
                    (size_t)(WU1B + kt * 16 + w * 4 + n2) * 512 + lane * 8];
                acc[n2] = __builtin_amdgcn_mfma_f32_16x16x32_bf16(Af, Bf, acc[n2], 0, 0, 0);
            }
        }
        if (grp == 0) {
            #pragma unroll
            for (int n2 = 0; n2 < 4; ++n2) {
                const int kc = (w * 4 + n2) * 16 + lane;
                const float wdeg = Wu1[(size_t)(2 * SD) * ID + kc];
                const float bb = bu1[kc];
                #pragma unroll
                for (int r = 0; r < 4; ++r)
                    uu[r * 256 + kc] =
                        ftanh(acc[n2][r] + bb + up[r * 260 + 256] * wdeg);
            }
        }
    }
    __syncthreads();

    {   // FC2 + residual: xs = h + tanh(uu@Wu2 + bu2); wave w -> nt {2w,2w+1}
        f32x4 acc[2];
        acc[0] = (f32x4){0.f, 0.f, 0.f, 0.f};
        acc[1] = (f32x4){0.f, 0.f, 0.f, 0.f};
        #pragma unroll
        for (int kt = 0; kt < 8; ++kt) {
            sh8 Af = afragT(uu, 256, kt, lane);
            #pragma unroll
            for (int n2 = 0; n2 < 2; ++n2) {
                sh8 Bf = *(const sh8*)&Bprep[
                    (size_t)(WU2B + kt * 8 + w * 2 + n2) * 512 + lane * 8];
                acc[n2] = __builtin_amdgcn_mfma_f32_16x16x32_bf16(Af, Bf, acc[n2], 0, 0, 0);
            }
        }
        if (grp == 0) {
            #pragma unroll
            for (int n2 = 0; n2 < 2; ++n2) {
                const int d = (w * 2 + n2) * 16 + lane;
                const float bb = bu2[d];
                #pragma unroll
                for (int r = 0; r < 4; ++r)
                    xsb[r * 128 + d] = up[r * 260 + d] + ftanh(acc[n2][r] + bb);
            }
        }
    }
    __syncthreads();

    {   // LayerNorm: wave w -> row w
        const float v0 = xsb[w * 128 + lane], v1 = xsb[w * 128 + lane + 64];
        float s = v0 + v1;
        #pragma unroll
        for (int m = 1; m < 64; m <<= 1) s += __shfl_xor(s, m, 64);
        const float mu = s * (1.0f / SD);
        const float d0 = v0 - mu, d1 = v1 - mu;
        float q = d0 * d0 + d1 * d1;
        #pragma unroll
        for (int m = 1; m < 64; m <<= 1) q += __shfl_xor(q, m, 64);
        const float inv = rsqrtf(q * (1.0f / SD) + 1e-5f);
        out[(size_t)(bi0 + w) * SD + lane] = d0 * inv * lnw[lane] + lnb[lane];
        out[(size_t)(bi0 + w) * SD + lane + 64] =
            d1 * inv * lnw[lane + 64] + lnb[lane + 64];
    }
}

extern "C" void kernel_launch(void* const* d_in, const int* in_sizes, int n_in,
                              void* d_out, int out_size, void* d_ws, size_t ws_size,
                              hipStream_t stream) {
    const float* h   = (const float*)d_in[0];
    const float* ef  = (const float*)d_in[1];
    const float* em  = (const float*)d_in[2];
    const float* Wm1 = (const float*)d_in[3];
    const float* bm1 = (const float*)d_in[4];
    const float* Wm2 = (const float*)d_in[5];
    const float* bm2 = (const float*)d_in[6];
    const float* Wg1 = (const float*)d_in[7];
    const float* bg1 = (const float*)d_in[8];
    const float* Wg2 = (const float*)d_in[9];
    const float* bg2 = (const float*)d_in[10];
    const float* Wu1 = (const float*)d_in[11];
    const float* bu1 = (const float*)d_in[12];
    const float* Wu2 = (const float*)d_in[13];
    const float* bu2 = (const float*)d_in[14];
    const float* lnw = (const float*)d_in[15];
    const float* lnb = (const float*)d_in[16];

    float* ws = (float*)d_ws;
    float* Hgi   = ws;
    float* Hgjt  = Hgi + (size_t)BN * ID;
    float* Hmi   = Hgjt + (size_t)BN * ID;
    float* Hmjt  = Hmi + (size_t)BN * ID;
    ushort* Bprep = (ushort*)(Hmjt + (size_t)BN * ID);
    float* outp = (float*)d_out;

    k_prep<<<544, 64, 0, stream>>>(Wg1, Wm1, Wm2, Wu1, Wu2, Bprep);
    k1_mfma<<<dim3(BN / 16, 4), 256, 0, stream>>>(h, bg1, bm1, Bprep,
                                                  Hgi, Hgjt, Hmi, Hmjt);
    k2_fused<<<BN / NI, 256, 0, stream>>>(ef, em, Bprep, Hgi, Hmi, Hgjt, Hmjt,
                                          Wg2, bg2, h, Wu1, bu1, bu2, bm2,
                                          lnw, lnb, outp);
}

// Round 15
// 120.215 us; speedup vs baseline: 2.1360x; 1.0316x over previous
//
#include <hip/hip_runtime.h>
#include <hip/hip_bf16.h>

#define BB 32
#define NN 128
#define SD 128
#define ED 32
#define ID 256
#define BN (BB*NN)   // 4096
#define NI 4         // i-blocks per k2 workgroup

// Bprep tile index bases
#define WM2B 288
#define WU1B 352
#define WU2B 480

typedef __attribute__((ext_vector_type(8))) short sh8;
typedef __attribute__((ext_vector_type(4))) float f32x4;

__device__ __forceinline__ float ftanh(float x) {
    float e2 = __expf(2.0f * x);
    return 1.0f - 2.0f * __builtin_amdgcn_rcpf(e2 + 1.0f);
}

__device__ __forceinline__ ushort f2bf(float f) {
    unsigned u = __float_as_uint(f);
    return (ushort)((u + 0x7FFF + ((u >> 16) & 1)) >> 16);
}

// build a bf16 A-frag (rows 0..3 real, 4..15 zero) from f32 LDS rows
__device__ __forceinline__ sh8 afragT(const float* base, int stride, int kt, int lane) {
    sh8 v = (sh8){0, 0, 0, 0, 0, 0, 0, 0};
    if ((lane & 15) < 4) {
        const float* p = base + (lane & 15) * stride + kt * 32 + (lane >> 4) * 8;
        f32x4 a0 = *(const f32x4*)p;
        f32x4 a1 = *(const f32x4*)(p + 4);
        v[0] = (short)f2bf(a0[0]); v[1] = (short)f2bf(a0[1]);
        v[2] = (short)f2bf(a0[2]); v[3] = (short)f2bf(a0[3]);
        v[4] = (short)f2bf(a1[0]); v[5] = (short)f2bf(a1[1]);
        v[6] = (short)f2bf(a1[2]); v[7] = (short)f2bf(a1[3]);
    }
    return v;
}

// ---------------------------------------------------------------------------
// k_prep: frag-ordered bf16 B-tiles.
// 0..255:   W1 h-parts [tgt(4)][kt(4)][nt(16)]
// 256..287: We rows 256..288 of W1 (16 gate + 16 msg)
// 288..351: Wm2 [kt(8)][nt(8)]     352..479: Wu1 rows 0..255 [kt(8)][nt(16)]
// 480..543: Wu2 [kt(8)][nt(8)]
// grid 544, block 64
// ---------------------------------------------------------------------------
__global__ void k_prep(const float* __restrict__ Wg1, const float* __restrict__ Wm1,
                       const float* __restrict__ Wm2, const float* __restrict__ Wu1,
                       const float* __restrict__ Wu2, ushort* __restrict__ Bprep) {
    const int tt = blockIdx.x;
    const int l = threadIdx.x;
    const float* W;
    int rowbase, nt, stride;
    if (tt < 256) {
        const int tgt = tt >> 6;
        const int kt = (tt >> 4) & 3;
        nt = tt & 15;
        W = (tgt >= 2) ? Wm1 : Wg1;
        rowbase = (tgt & 1) * 128 + kt * 32;
        stride = ID;
    } else if (tt < WM2B) {
        const int wt = tt - 256;
        W = (wt >> 4) ? Wm1 : Wg1;
        rowbase = 2 * SD;
        nt = wt & 15;
        stride = ID;
    } else if (tt < WU1B) {
        const int wt = tt - WM2B;
        W = Wm2; rowbase = (wt >> 3) * 32; nt = wt & 7; stride = SD;
    } else if (tt < WU2B) {
        const int wt = tt - WU1B;
        W = Wu1; rowbase = (wt >> 4) * 32; nt = wt & 15; stride = ID;
    } else {
        const int wt = tt - WU2B;
        W = Wu2; rowbase = (wt >> 3) * 32; nt = wt & 7; stride = SD;
    }
    const int colw = nt * 16 + (l & 15);
    const int kb = rowbase + (l >> 4) * 8;
    sh8 v;
    #pragma unroll
    for (int e = 0; e < 8; ++e)
        v[e] = (short)f2bf(W[(size_t)(kb + e) * stride + colw]);
    *(sh8*)&Bprep[(size_t)tt * 512 + l * 8] = v;
}

// ---------------------------------------------------------------------------
// K1 (MFMA): one 16-row stripe x one target per block (grid.y = tgt).
//  tgt 0: Hgi = h@Wg1[0:128]+bg1 (normal)   1: Hgjt (frag tiles)
//  tgt 2: Hmi = h@Wm1[0:128]+bm1 (normal)   3: Hmjt (frag tiles)
// grid (BN/16, 4), block 256
// ---------------------------------------------------------------------------
__global__ __launch_bounds__(256) void k1_mfma(
        const float* __restrict__ h,
        const float* __restrict__ bg1, const float* __restrict__ bm1,
        const ushort* __restrict__ Bprep,
        float* __restrict__ Hgi, float* __restrict__ Hgjt,
        float* __restrict__ Hmi, float* __restrict__ Hmjt) {
    const int blk = blockIdx.x;
    const int tgt = blockIdx.y;
    const int t = threadIdx.x;
    const int w = t >> 6;
    const int lane = t & 63;
    const int col = lane & 15;
    const int grp = lane >> 4;
    __shared__ __align__(16) ushort Alds[4 * 512];

    {   // stage h rows -> bf16 frag order
        const int c = t;
        const int kt = c >> 6, l = c & 63;
        const int row = l & 15;
        const int kb = kt * 32 + (l >> 4) * 8;
        const float* p = h + (size_t)(blk * 16 + row) * SD + kb;
        f32x4 a0 = *(const f32x4*)p;
        f32x4 a1 = *(const f32x4*)(p + 4);
        sh8 v;
        v[0] = (short)f2bf(a0[0]); v[1] = (short)f2bf(a0[1]);
        v[2] = (short)f2bf(a0[2]); v[3] = (short)f2bf(a0[3]);
        v[4] = (short)f2bf(a1[0]); v[5] = (short)f2bf(a1[1]);
        v[6] = (short)f2bf(a1[2]); v[7] = (short)f2bf(a1[3]);
        *(sh8*)&Alds[c * 8] = v;
    }
    __syncthreads();

    const int kcol = w * 64 + col;
    sh8 Af[4];
    #pragma unroll
    for (int kt = 0; kt < 4; ++kt)
        Af[kt] = *(const sh8*)&Alds[kt * 512 + lane * 8];

    f32x4 acc[4];
    #pragma unroll
    for (int n = 0; n < 4; ++n) acc[n] = (f32x4){0.f, 0.f, 0.f, 0.f};
    #pragma unroll
    for (int kt = 0; kt < 4; ++kt)
        #pragma unroll
        for (int n = 0; n < 4; ++n) {
            sh8 Bf = *(const sh8*)&Bprep[
                (size_t)(tgt * 64 + kt * 16 + w * 4 + n) * 512 + lane * 8];
            acc[n] = __builtin_amdgcn_mfma_f32_16x16x32_bf16(
                Af[kt], Bf, acc[n], 0, 0, 0);
        }
    if (tgt & 1) {          // frag-tile store (gj / mj)
        float* out = (tgt == 1) ? Hgjt : Hmjt;
        #pragma unroll
        for (int n = 0; n < 4; ++n)
            *(f32x4*)&out[((size_t)blk * ID + kcol + n * 16) * 16 + grp * 4] = acc[n];
    } else {                // normal layout + bias (gi / mi)
        const float* bias = (tgt == 0) ? bg1 : bm1;
        float* out = (tgt == 0) ? Hgi : Hmi;
        #pragma unroll
        for (int n = 0; n < 4; ++n) {
            const float bv = bias[kcol + n * 16];
            #pragma unroll
            for (int r = 0; r < 4; ++r)
                out[(size_t)(blk * 16 + grp * 4 + r) * ID + kcol + n * 16] =
                    acc[n][r] + bv;
        }
    }
}

// ---------------------------------------------------------------------------
// K2 fused: edge passes (R5 form) + MFMA tail (agg/FC1/FC2 as M=16 bf16
// MFMAs with 4 live rows) + residual + LayerNorm. grid BN/NI, block 256
// ---------------------------------------------------------------------------
__global__ __launch_bounds__(256, 4) void k2_fused(
        const float* __restrict__ ef, const float* __restrict__ em,
        const ushort* __restrict__ Bprep,
        const float* __restrict__ Hgi, const float* __restrict__ Hmi,
        const float* __restrict__ Hgjt, const float* __restrict__ Hmjt,
        const float* __restrict__ Wg2, const float* __restrict__ bg2,
        const float* __restrict__ h,
        const float* __restrict__ Wu1, const float* __restrict__ bu1,
        const float* __restrict__ bu2, const float* __restrict__ bm2,
        const float* __restrict__ lnw, const float* __restrict__ lnb,
        float* __restrict__ out) {
    const int bi0 = blockIdx.x * NI;
    const int b = bi0 >> 7;
    const int t = threadIdx.x;
    const int w = t >> 6;
    const int lane = t & 63;
    const int col = lane & 15;
    const int grp = lane >> 4;

    __shared__ __align__(16) ushort Elds[NI * 8 * 512];   // 32 KB
    __shared__ float glds[NI][NN];                        // 2 KB
    __shared__ float red[2][4][2];
    __shared__ float gsumL[NI], degL[NI];

    {
        float* gl = &glds[0][0];
        gl[t] = 0.f;
        gl[t + 256] = 0.f;
    }
    #pragma unroll
    for (int i = 0; i < NI; ++i) {
        const float* efb = ef + (size_t)(bi0 + i) * NN * ED;
        #pragma unroll
        for (int it = 0; it < 2; ++it) {
            const int c = it * 256 + t;                    // chunk 0..511
            const int j = ((c >> 6) << 4) | (c & 15);
            const int kb = ((c >> 4) & 3) * 8;
            const float* p = efb + j * ED + kb;
            f32x4 a0 = *(const f32x4*)p;
            f32x4 a1 = *(const f32x4*)(p + 4);
            sh8 v;
            v[0] = (short)f2bf(a0[0]); v[1] = (short)f2bf(a0[1]);
            v[2] = (short)f2bf(a0[2]); v[3] = (short)f2bf(a0[3]);
            v[4] = (short)f2bf(a1[0]); v[5] = (short)f2bf(a1[1]);
            v[6] = (short)f2bf(a1[2]); v[7] = (short)f2bf(a1[3]);
            *(sh8*)&Elds[i * 4096 + c * 8] = v;
        }
    }
    __syncthreads();

    const int kcol = w * 64 + col;
    sh8 Bg[4], Bm[4];
    #pragma unroll
    for (int n = 0; n < 4; ++n) {
        Bg[n] = *(const sh8*)&Bprep[(size_t)(256 + w * 4 + n) * 512 + lane * 8];
        Bm[n] = *(const sh8*)&Bprep[(size_t)(272 + w * 4 + n) * 512 + lane * 8];
    }
    const float* HgjL = Hgjt + (size_t)b * 8 * ID * 16 + (size_t)kcol * 16 + grp * 4;
    const float* HmjL = Hmjt + (size_t)b * 8 * ID * 16 + (size_t)kcol * 16 + grp * 4;

    // ================= gate pass
    {
        float hgiR[NI][4], wg2R[4];
        #pragma unroll
        for (int n = 0; n < 4; ++n) wg2R[n] = Wg2[kcol + n * 16];
        #pragma unroll
        for (int i = 0; i < NI; ++i)
            #pragma unroll
            for (int n = 0; n < 4; ++n)
                hgiR[i][n] = Hgi[(size_t)(bi0 + i) * ID + kcol + n * 16];
        f32x4 Cg[4], Cn[4];
        #pragma unroll
        for (int n = 0; n < 4; ++n) Cg[n] = *(const f32x4*)(HgjL + n * 256);
        for (int s = 0; s < 8; ++s) {
            if (s < 7) {
                const float* ps = HgjL + (s + 1) * (ID * 16);
                #pragma unroll
                for (int n = 0; n < 4; ++n) Cn[n] = *(const f32x4*)(ps + n * 256);
            }
            #pragma unroll
            for (int i = 0; i < NI; ++i) {
                sh8 Af = *(const sh8*)&Elds[i * 4096 + s * 512 + lane * 8];
                f32x4 acc[4];
                #pragma unroll
                for (int n = 0; n < 4; ++n)
                    acc[n] = __builtin_amdgcn_mfma_f32_16x16x32_bf16(
                        Af, Bg[n], Cg[n], 0, 0, 0);
                float p[4] = {0.f, 0.f, 0.f, 0.f};
                #pragma unroll
                for (int n = 0; n < 4; ++n)
                    #pragma unroll
                    for (int r = 0; r < 4; ++r)
                        p[r] = fmaf(ftanh(acc[n][r] + hgiR[i][n]), wg2R[n], p[r]);
                #pragma unroll
                for (int m = 1; m < 16; m <<= 1)
                    #pragma unroll
                    for (int r = 0; r < 4; ++r) p[r] += __shfl_xor(p[r], m, 64);
                if (col == 0) {
                    #pragma unroll
                    for (int r = 0; r < 4; ++r)
                        atomicAdd(&glds[i][s * 16 + grp * 4 + r], p[r]);
                }
            }
            #pragma unroll
            for (int n = 0; n < 4; ++n) Cg[n] = Cn[n];
        }
    }
    __syncthreads();

    // ---- sigmoid + mask, gsum/deg reductions (to LDS)
    {
        const float bg2v = bg2[0];
        #pragma unroll
        for (int it = 0; it < NI / 2; ++it) {
            const int i = it * 2 + (t >> 7);
            const int j = t & 127;
            const float pre = glds[i][j] + bg2v;
            const float m = em[(size_t)(bi0 + i) * NN + j];
            const float g = m * __builtin_amdgcn_rcpf(1.0f + __expf(-pre));
            glds[i][j] = g;
            float gsv = g, dv = m;
            #pragma unroll
            for (int mm = 1; mm < 64; mm <<= 1) {
                gsv += __shfl_xor(gsv, mm, 64);
                dv  += __shfl_xor(dv, mm, 64);
            }
            if (lane == 0) { red[it][w][0] = gsv; red[it][w][1] = dv; }
        }
    }
    __syncthreads();
    if (t < NI) {
        const int it = t >> 1, w0 = (t & 1) * 2;
        gsumL[t] = red[it][w0][0] + red[it][w0 + 1][0];
        degL[t]  = red[it][w0][1] + red[it][w0 + 1][1];
    }

    // ================= msg pass
    float ts[NI][4];
    {
        float hmiR[NI][4];
        #pragma unroll
        for (int i = 0; i < NI; ++i)
            #pragma unroll
            for (int n = 0; n < 4; ++n)
                hmiR[i][n] = Hmi[(size_t)(bi0 + i) * ID + kcol + n * 16];
        #pragma unroll
        for (int i = 0; i < NI; ++i)
            #pragma unroll
            for (int n = 0; n < 4; ++n) ts[i][n] = 0.f;
        f32x4 Cm[4], Cn[4];
        #pragma unroll
        for (int n = 0; n < 4; ++n) Cm[n] = *(const f32x4*)(HmjL + n * 256);
        for (int s = 0; s < 8; ++s) {
            if (s < 7) {
                const float* ps = HmjL + (s + 1) * (ID * 16);
                #pragma unroll
                for (int n = 0; n < 4; ++n) Cn[n] = *(const f32x4*)(ps + n * 256);
            }
            #pragma unroll
            for (int i = 0; i < NI; ++i) {
                sh8 Af = *(const sh8*)&Elds[i * 4096 + s * 512 + lane * 8];
                f32x4 acc[4];
                #pragma unroll
                for (int n = 0; n < 4; ++n)
                    acc[n] = __builtin_amdgcn_mfma_f32_16x16x32_bf16(
                        Af, Bm[n], Cm[n], 0, 0, 0);
                f32x4 gr = *(const f32x4*)&glds[i][s * 16 + grp * 4];
                #pragma unroll
                for (int n = 0; n < 4; ++n)
                    #pragma unroll
                    for (int r = 0; r < 4; ++r)
                        ts[i][n] = fmaf(gr[r], ftanh(acc[n][r] + hmiR[i][n]),
                                        ts[i][n]);
            }
            #pragma unroll
            for (int n = 0; n < 4; ++n) Cm[n] = Cn[n];
        }
        #pragma unroll
        for (int i = 0; i < NI; ++i)
            #pragma unroll
            for (int n = 0; n < 4; ++n) {
                ts[i][n] += __shfl_xor(ts[i][n], 16, 64);
                ts[i][n] += __shfl_xor(ts[i][n], 32, 64);
            }
    }

    // ================= MFMA tail (reuse Elds as f32 scratch)
    __syncthreads();                      // all Elds/glds reads done
    float* scratch = (float*)Elds;
    float* Tl  = scratch;                 // [4][256]
    float* up  = scratch + 1024;          // [4][260]
    float* uu  = scratch + 2064;          // [4][256]
    float* xsb = scratch + 3088;          // [4][128]
    if (lane < 16) {
        #pragma unroll
        for (int i = 0; i < NI; ++i)
            #pragma unroll
            for (int n = 0; n < 4; ++n)
                Tl[i * 256 + w * 64 + n * 16 + lane] = ts[i][n];
    }
    #pragma unroll
    for (int it = 0; it < 2; ++it) {
        const int idx = it * 256 + t;
        const int i = idx >> 7, c = idx & 127;
        up[i * 260 + c] = h[(size_t)(bi0 + i) * SD + c];
    }
    if (t < NI) up[t * 260 + 256] = degL[t] * (1.0f / 127.0f);
    __syncthreads();

    {   // agg: up[i][128+d] = (T@Wm2 + g*bm2)/max(g,1); wave w -> nt {2w,2w+1}
        f32x4 acc[2];
        acc[0] = (f32x4){0.f, 0.f, 0.f, 0.f};
        acc[1] = (f32x4){0.f, 0.f, 0.f, 0.f};
        #pragma unroll
        for (int kt = 0; kt < 8; ++kt) {
            sh8 Af = afragT(Tl, 256, kt, lane);
            #pragma unroll
            for (int n2 = 0; n2 < 2; ++n2) {
                sh8 Bf = *(const sh8*)&Bprep[
                    (size_t)(WM2B + kt * 8 + w * 2 + n2) * 512 + lane * 8];
                acc[n2] = __builtin_amdgcn_mfma_f32_16x16x32_bf16(Af, Bf, acc[n2], 0, 0, 0);
            }
        }
        if (grp == 0) {
            #pragma unroll
            for (int n2 = 0; n2 < 2; ++n2) {
                const int d = (w * 2 + n2) * 16 + lane;
                const float bmv = bm2[d];
                #pragma unroll
                for (int r = 0; r < 4; ++r) {
                    const float g = gsumL[r];
                    up[r * 260 + SD + d] = fmaf(g, bmv, acc[n2][r]) *
                                           __builtin_amdgcn_rcpf(fmaxf(g, 1.0f));
                }
            }
        }
    }
    __syncthreads();

    {   // FC1: uu = tanh(up@Wu1 + bu1 + deg-row); wave w -> nt {4w..4w+3}
        f32x4 acc[4];
        #pragma unroll
        for (int n2 = 0; n2 < 4; ++n2) acc[n2] = (f32x4){0.f, 0.f, 0.f, 0.f};
        #pragma unroll
        for (int kt = 0; kt < 8; ++kt) {
            sh8 Af = afragT(up, 260, kt, lane);
            #pragma unroll
            for (int n2 = 0; n2 < 4; ++n2) {
                sh8 Bf = *(const sh8*)&Bprep[
                    (size_t)(WU1B + kt * 16 + w * 4 + n2) * 512 + lane * 8];
                acc[n2] = __builtin_amdgcn_mfma_f32_16x16x32_bf16(Af, Bf, acc[n2], 0, 0, 0);
            }
        }
        if (grp == 0) {
            #pragma unroll
            for (int n2 = 0; n2 < 4; ++n2) {
                const int kc = (w * 4 + n2) * 16 + lane;
                const float wdeg = Wu1[(size_t)(2 * SD) * ID + kc];
                const float bb = bu1[kc];
                #pragma unroll
                for (int r = 0; r < 4; ++r)
                    uu[r * 256 + kc] =
                        ftanh(acc[n2][r] + bb + up[r * 260 + 256] * wdeg);
            }
        }
    }
    __syncthreads();

    {   // FC2 + residual: xs = h + tanh(uu@Wu2 + bu2); wave w -> nt {2w,2w+1}
        f32x4 acc[2];
        acc[0] = (f32x4){0.f, 0.f, 0.f, 0.f};
        acc[1] = (f32x4){0.f, 0.f, 0.f, 0.f};
        #pragma unroll
        for (int kt = 0; kt < 8; ++kt) {
            sh8 Af = afragT(uu, 256, kt, lane);
            #pragma unroll
            for (int n2 = 0; n2 < 2; ++n2) {
                sh8 Bf = *(const sh8*)&Bprep[
                    (size_t)(WU2B + kt * 8 + w * 2 + n2) * 512 + lane * 8];
                acc[n2] = __builtin_amdgcn_mfma_f32_16x16x32_bf16(Af, Bf, acc[n2], 0, 0, 0);
            }
        }
        if (grp == 0) {
            #pragma unroll
            for (int n2 = 0; n2 < 2; ++n2) {
                const int d = (w * 2 + n2) * 16 + lane;
                const float bb = bu2[d];
                #pragma unroll
                for (int r = 0; r < 4; ++r)
                    xsb[r * 128 + d] = up[r * 260 + d] + ftanh(acc[n2][r] + bb);
            }
        }
    }
    __syncthreads();

    {   // LayerNorm: wave w -> row w
        const float v0 = xsb[w * 128 + lane], v1 = xsb[w * 128 + lane + 64];
        float s = v0 + v1;
        #pragma unroll
        for (int m = 1; m < 64; m <<= 1) s += __shfl_xor(s, m, 64);
        const float mu = s * (1.0f / SD);
        const float d0 = v0 - mu, d1 = v1 - mu;
        float q = d0 * d0 + d1 * d1;
        #pragma unroll
        for (int m = 1; m < 64; m <<= 1) q += __shfl_xor(q, m, 64);
        const float inv = rsqrtf(q * (1.0f / SD) + 1e-5f);
        out[(size_t)(bi0 + w) * SD + lane] = d0 * inv * lnw[lane] + lnb[lane];
        out[(size_t)(bi0 + w) * SD + lane + 64] =
            d1 * inv * lnw[lane + 64] + lnb[lane + 64];
    }
}

extern "C" void kernel_launch(void* const* d_in, const int* in_sizes, int n_in,
                              void* d_out, int out_size, void* d_ws, size_t ws_size,
                              hipStream_t stream) {
    const float* h   = (const float*)d_in[0];
    const float* ef  = (const float*)d_in[1];
    const float* em  = (const float*)d_in[2];
    const float* Wm1 = (const float*)d_in[3];
    const float* bm1 = (const float*)d_in[4];
    const float* Wm2 = (const float*)d_in[5];
    const float* bm2 = (const float*)d_in[6];
    const float* Wg1 = (const float*)d_in[7];
    const float* bg1 = (const float*)d_in[8];
    const float* Wg2 = (const float*)d_in[9];
    const float* bg2 = (const float*)d_in[10];
    const float* Wu1 = (const float*)d_in[11];
    const float* bu1 = (const float*)d_in[12];
    const float* Wu2 = (const float*)d_in[13];
    const float* bu2 = (const float*)d_in[14];
    const float* lnw = (const float*)d_in[15];
    const float* lnb = (const float*)d_in[16];

    float* ws = (float*)d_ws;
    float* Hgi   = ws;
    float* Hgjt  = Hgi + (size_t)BN * ID;
    float* Hmi   = Hgjt + (size_t)BN * ID;
    float* Hmjt  = Hmi + (size_t)BN * ID;
    ushort* Bprep = (ushort*)(Hmjt + (size_t)BN * ID);
    float* outp = (float*)d_out;

    k_prep<<<544, 64, 0, stream>>>(Wg1, Wm1, Wm2, Wu1, Wu2, Bprep);
    k1_mfma<<<dim3(BN / 16, 4), 256, 0, stream>>>(h, bg1, bm1, Bprep,
                                                  Hgi, Hgjt, Hmi, Hmjt);
    k2_fused<<<BN / NI, 256, 0, stream>>>(ef, em, Bprep, Hgi, Hmi, Hgjt, Hmjt,
                                          Wg2, bg2, h, Wu1, bu1, bu2, bm2,
                                          lnw, lnb, outp);
}